// Round 1
// baseline (141.555 us; speedup 1.0000x reference)
//
#include <hip/hip_runtime.h>
#include <math.h>

#define NB 16
#define NC 256
#define NHW 1024
#define NE 512
#define NGQ 8      // quantum groups
#define NDQ 4      // data qubits
#define NLQ 4      // layers
#define NQB 6      // qubits
#define QDIM 64
#define PIX 32     // pixels per block in main kernel
#define XS_STRIDE 36   // padded LDS stride (16B aligned: 36*4=144)

// ---- CNOT-ring permutation (compile-time) ----
struct PermT { int v[QDIM]; };
constexpr PermT make_perm() {
    PermT P{};
    int f[QDIM] = {};
    for (int i = 0; i < QDIM; ++i) f[i] = i;
    for (int c = 0; c < NQB; ++c) {
        int t = (c + 1) % NQB;
        for (int i = 0; i < QDIM; ++i)
            if ((f[i] >> (NQB - 1 - c)) & 1) f[i] ^= 1 << (NQB - 1 - t);
    }
    for (int i = 0; i < QDIM; ++i) P.v[f[i]] = i;   // inverse map
    return P;
}
constexpr PermT PERM = make_perm();

// ---- Kernel 1: GroupNorm stats (one block per (b, gn_group)) ----
__global__ __launch_bounds__(256) void k_stats(const float* __restrict__ x,
                                               float* __restrict__ mu,
                                               float* __restrict__ rs) {
    int bg = blockIdx.x;  // b*32 + g ; channels of group are contiguous
    const float4* xp = (const float4*)(x + (size_t)bg * 8 * NHW);
    float s = 0.f, ss = 0.f;
    for (int i = threadIdx.x; i < 8 * NHW / 4; i += 256) {
        float4 v = xp[i];
        s  += v.x + v.y + v.z + v.w;
        ss += v.x*v.x + v.y*v.y + v.z*v.z + v.w*v.w;
    }
    __shared__ float red0[4], red1[4];
    #pragma unroll
    for (int o = 32; o; o >>= 1) { s += __shfl_down(s, o); ss += __shfl_down(ss, o); }
    int lane = threadIdx.x & 63, w = threadIdx.x >> 6;
    if (lane == 0) { red0[w] = s; red1[w] = ss; }
    __syncthreads();
    if (threadIdx.x == 0) {
        s  = red0[0] + red0[1] + red0[2] + red0[3];
        ss = red1[0] + red1[1] + red1[2] + red1[3];
        float m = s * (1.f / 8192.f);
        float var = ss * (1.f / 8192.f) - m * m;
        mu[bg] = m;
        rs[bg] = rsqrtf(var + 1e-5f);
    }
}

// ---- Kernel 2: A[b][j] = theta[j] + silu(emb[b]) . w_style[j] + b_style[j] ----
__global__ __launch_bounds__(256) void k_style(const float* __restrict__ emb,
                                               const float* __restrict__ w_style,
                                               const float* __restrict__ b_style,
                                               const float* __restrict__ theta,
                                               float* __restrict__ A) {
    int b = blockIdx.x;
    __shared__ float es[NE];
    int t = threadIdx.x;
    for (int i = t; i < NE; i += 256) {
        float v = emb[b * NE + i];
        es[i] = v / (1.f + __expf(-v));
    }
    __syncthreads();
    int j0 = t >> 3, sub = t & 7;   // 8 lanes per output, 32 outputs per pass
    for (int pass = 0; pass < 6; ++pass) {
        int j = pass * 32 + j0;
        const float* wr = w_style + (size_t)j * NE + sub * 64;
        const float* er = es + sub * 64;
        float acc = 0.f;
        #pragma unroll
        for (int i = 0; i < 64; i += 4) {
            float4 w4 = *(const float4*)(wr + i);
            acc = fmaf(w4.x, er[i],   acc);
            acc = fmaf(w4.y, er[i+1], acc);
            acc = fmaf(w4.z, er[i+2], acc);
            acc = fmaf(w4.w, er[i+3], acc);
        }
        acc += __shfl_xor(acc, 1);
        acc += __shfl_xor(acc, 2);
        acc += __shfl_xor(acc, 4);
        if (sub == 0) A[b * 192 + j] = theta[j] + b_style[j] + acc;
    }
}

// ---- Kernel 3: fused norm-apply + ang matvec + circuits + out matvec + residual ----
__global__ __launch_bounds__(256, 2) void k_main(const float* __restrict__ x,
                                                 const float* __restrict__ gamma,
                                                 const float* __restrict__ beta,
                                                 const float* __restrict__ w_in,
                                                 const float* __restrict__ b_in,
                                                 const float* __restrict__ A,
                                                 const float* __restrict__ w_out,
                                                 const float* __restrict__ b_out,
                                                 const float* __restrict__ mu,
                                                 const float* __restrict__ rs,
                                                 float* __restrict__ out) {
    __shared__ float xs[NC * XS_STRIDE];  // normalized x, 36 KB
    __shared__ float as_[32 * 32];        // ang  (o, p), 4 KB
    __shared__ float ms[32 * 32];         // meas (o, p), 4 KB

    int blk = blockIdx.x;
    int b = blk >> 5;                 // 32 pixel-chunks per image
    int pbase = (blk & 31) * PIX;
    int t = threadIdx.x;

    // Phase 1: stage normalized x tile (256 ch x 32 pix)
    {
        int c0 = t >> 3, f4 = (t & 7) * 4;
        #pragma unroll
        for (int k = 0; k < 8; ++k) {
            int c = c0 + 32 * k;
            int gidx = b * 32 + (c >> 3);
            float m = mu[gidx], r = rs[gidx];
            float sc = r * gamma[c];
            float sh = beta[c] - m * sc;
            float4 x4 = *(const float4*)(x + (size_t)(b * NC + c) * NHW + pbase + f4);
            float4 h4;
            h4.x = fmaf(x4.x, sc, sh);
            h4.y = fmaf(x4.y, sc, sh);
            h4.z = fmaf(x4.z, sc, sh);
            h4.w = fmaf(x4.w, sc, sh);
            *(float4*)(xs + c * XS_STRIDE + f4) = h4;
        }
    }
    __syncthreads();

    // Phase 2: ang[o][p] = w_in[o] . h[:, p] + b_in[o]
    {
        int o = t >> 3, f4 = (t & 7) * 4;
        const float* wr = w_in + o * NC;
        float4 acc = {0.f, 0.f, 0.f, 0.f};
        #pragma unroll 4
        for (int c = 0; c < NC; c += 4) {
            float4 w4 = *(const float4*)(wr + c);
            const float* xc = xs + c * XS_STRIDE + f4;
            float4 h0 = *(const float4*)(xc);
            float4 h1 = *(const float4*)(xc + XS_STRIDE);
            float4 h2 = *(const float4*)(xc + 2 * XS_STRIDE);
            float4 h3 = *(const float4*)(xc + 3 * XS_STRIDE);
            acc.x = fmaf(w4.x, h0.x, fmaf(w4.y, h1.x, fmaf(w4.z, h2.x, fmaf(w4.w, h3.x, acc.x))));
            acc.y = fmaf(w4.x, h0.y, fmaf(w4.y, h1.y, fmaf(w4.z, h2.y, fmaf(w4.w, h3.y, acc.y))));
            acc.z = fmaf(w4.x, h0.z, fmaf(w4.y, h1.z, fmaf(w4.z, h2.z, fmaf(w4.w, h3.z, acc.z))));
            acc.w = fmaf(w4.x, h0.w, fmaf(w4.y, h1.w, fmaf(w4.z, h2.w, fmaf(w4.w, h3.w, acc.w))));
        }
        float bi = b_in[o];
        float4 r = {acc.x + bi, acc.y + bi, acc.z + bi, acc.w + bi};
        *(float4*)(as_ + o * 32 + f4) = r;
    }
    __syncthreads();

    // Phase 3: quantum circuits — one thread per (pixel, group)
    {
        int p = t & 31, g = t >> 5;
        float angp[NDQ];
        #pragma unroll
        for (int d = 0; d < NDQ; ++d) angp[d] = as_[(g * NDQ + d) * 32 + p];
        const float* Ab = A + b * 192 + g * 24;

        float st[QDIM];
        #pragma unroll
        for (int i = 0; i < QDIM; ++i) st[i] = 0.f;
        st[0] = 1.f;

        #pragma unroll
        for (int l = 0; l < NLQ; ++l) {
            #pragma unroll
            for (int q = 0; q < NQB; ++q) {
                float a = Ab[l * NQB + q] + (q < NDQ ? angp[q] : 0.f);
                float sn, cs;
                __sincosf(0.5f * a, &sn, &cs);
                const int m = 32 >> q;
                #pragma unroll
                for (int i = 0; i < QDIM; ++i) {
                    if (i & m) continue;
                    float a0 = st[i], a1 = st[i | m];
                    st[i]     = cs * a0 - sn * a1;
                    st[i | m] = sn * a0 + cs * a1;
                }
            }
            float tmp[QDIM];
            #pragma unroll
            for (int i = 0; i < QDIM; ++i) tmp[i] = st[PERM.v[i]];
            #pragma unroll
            for (int i = 0; i < QDIM; ++i) st[i] = tmp[i];
        }

        // probs -> 4 Z expectations
        float pr[QDIM];
        #pragma unroll
        for (int i = 0; i < QDIM; ++i) pr[i] = st[i] * st[i];
        #pragma unroll
        for (int d = 0; d < NDQ; ++d) {
            const int mb = 32 >> d;
            float acc = 0.f;
            #pragma unroll
            for (int i = 0; i < QDIM; ++i) acc += (i & mb) ? -pr[i] : pr[i];
            ms[(g * NDQ + d) * 32 + p] = acc;
        }
    }
    __syncthreads();

    // Phase 4: out[c][p] = w_out[c] . meas[:, p] + b_out[c] + x[c][p]
    {
        int c0 = t >> 3, f4 = (t & 7) * 4;
        #pragma unroll
        for (int k = 0; k < 8; ++k) {
            int c = c0 + 32 * k;
            const float* wr = w_out + c * 32;
            float4 acc = {0.f, 0.f, 0.f, 0.f};
            #pragma unroll
            for (int o = 0; o < 32; o += 4) {
                float4 w4 = *(const float4*)(wr + o);
                const float* mc = ms + o * 32 + f4;
                float4 m0 = *(const float4*)(mc);
                float4 m1 = *(const float4*)(mc + 32);
                float4 m2 = *(const float4*)(mc + 64);
                float4 m3 = *(const float4*)(mc + 96);
                acc.x = fmaf(w4.x, m0.x, fmaf(w4.y, m1.x, fmaf(w4.z, m2.x, fmaf(w4.w, m3.x, acc.x))));
                acc.y = fmaf(w4.x, m0.y, fmaf(w4.y, m1.y, fmaf(w4.z, m2.y, fmaf(w4.w, m3.y, acc.y))));
                acc.z = fmaf(w4.x, m0.z, fmaf(w4.y, m1.z, fmaf(w4.z, m2.z, fmaf(w4.w, m3.z, acc.z))));
                acc.w = fmaf(w4.x, m0.w, fmaf(w4.y, m1.w, fmaf(w4.z, m2.w, fmaf(w4.w, m3.w, acc.w))));
            }
            size_t gidx = (size_t)(b * NC + c) * NHW + pbase + f4;
            float4 x4 = *(const float4*)(x + gidx);
            float bo = b_out[c];
            float4 r;
            r.x = acc.x + bo + x4.x;
            r.y = acc.y + bo + x4.y;
            r.z = acc.z + bo + x4.z;
            r.w = acc.w + bo + x4.w;
            *(float4*)(out + gidx) = r;
        }
    }
}

extern "C" void kernel_launch(void* const* d_in, const int* in_sizes, int n_in,
                              void* d_out, int out_size, void* d_ws, size_t ws_size,
                              hipStream_t stream) {
    const float* x       = (const float*)d_in[0];
    const float* emb     = (const float*)d_in[1];
    const float* gamma   = (const float*)d_in[2];
    const float* beta    = (const float*)d_in[3];
    const float* w_in    = (const float*)d_in[4];
    const float* b_in    = (const float*)d_in[5];
    const float* theta   = (const float*)d_in[6];
    const float* w_style = (const float*)d_in[7];
    const float* b_style = (const float*)d_in[8];
    const float* w_out   = (const float*)d_in[9];
    const float* b_out   = (const float*)d_in[10];
    float* out = (float*)d_out;

    float* ws = (float*)d_ws;
    float* mu = ws;           // 512
    float* rs = ws + 512;     // 512
    float* A  = ws + 1024;    // 16*192 = 3072

    k_stats<<<NB * 32, 256, 0, stream>>>(x, mu, rs);
    k_style<<<NB, 256, 0, stream>>>(emb, w_style, b_style, theta, A);
    k_main<<<NB * 32, 256, 0, stream>>>(x, gamma, beta, w_in, b_in, A,
                                        w_out, b_out, mu, rs, out);
}